// Round 16
// baseline (25.765 us; speedup 1.0000x reference)
//
#include <hip/hip_runtime.h>
#include <hip/hip_fp16.h>
#include <math.h>

#define NG 2048
#define FEATN 128
#define NBLK 256
#define LOG2E 1.4426950408889634f
#define MAGIC1 0x7F3DC0DEu
#define MAGIC2 0x6B42F00Du

typedef unsigned long long u64;

// ws byte layout:
//   RAW0 u64[2048] @0      f16x4 {u,v,rx,ry}    (cull record)
//   RAW1 f4[2048] @16384   {u,v,a2,b2}
//   RAW2 f4[2048] @49152   {c2,op,rg(bf16x2),b}
//   KEY  u32[2048] @81920  tz bits (ties by index)
//   S0 u64[2048] @98304 | S1 f4[2048] @131072 | S2 f4[2048] @163840  (depth-sorted)
//   FLAG1 u32[256] @229376 | FLAG2 u32[256] @230400
#define RAW1_B 16384
#define RAW2_B 49152
#define KEY_B  81920
#define S0_B   98304
#define S1_B   131072
#define S2_B   163840
#define F1_B   229376
#define F2_B   230400

__device__ __forceinline__ float sigmoidf_(float z) { return 1.0f / (1.0f + expf(-z)); }

// write path: relaxed agent-scope atomic stores (L1/L2-bypass -> LLC); reads after
// barriers are plain cached loads (lines never cache-read pre-barrier; replay-stale
// content is bit-identical because the kernel is deterministic).
__device__ __forceinline__ void stg8(void* p, u64 v) {
    __hip_atomic_store((u64*)p, v, __ATOMIC_RELAXED, __HIP_MEMORY_SCOPE_AGENT);
}
__device__ __forceinline__ void stg4(unsigned* p, unsigned v) {
    __hip_atomic_store(p, v, __ATOMIC_RELAXED, __HIP_MEMORY_SCOPE_AGENT);
}
__device__ __forceinline__ unsigned ldg4(const unsigned* p) {
    return __hip_atomic_load(p, __ATOMIC_RELAXED, __HIP_MEMORY_SCOPE_AGENT);
}
__device__ __forceinline__ void st_f4(void* p, float4 v) {
    union { float2 f; u64 u; } a, b;
    a.f = make_float2(v.x, v.y); b.f = make_float2(v.z, v.w);
    stg8(p, a.u); stg8((char*)p + 8, b.u);
}
__device__ __forceinline__ unsigned short bf16_(float f) {
    unsigned u = __float_as_uint(f);
    return (unsigned short)((u + 0x8000u) >> 16);
}

__global__ __launch_bounds__(1024) void k_fused(
    const float* __restrict__ x, const float* __restrict__ pts, const float* __restrict__ vm,
    const float* __restrict__ w_shs, const float* __restrict__ b_shs,
    const float* __restrict__ w_scale, const float* __restrict__ b_scale,
    const float* __restrict__ w_xyz, const float* __restrict__ b_xyz,
    const float* __restrict__ w_opac, const float* __restrict__ b_opac,
    const float* __restrict__ w_rot, const float* __restrict__ b_rot,
    float* __restrict__ ws, float* __restrict__ out)
{
    // smem_u overlays: phaseA accs[8][14] | rank skey32 u32[2048] | phaseB params_lds[1024][8]
    __shared__ __attribute__((aligned(16))) char smem_u[1024 * 8 * 4];
    __shared__ unsigned short sidx16[NG];
    __shared__ float partT[16][64], partR[16][64], partG[16][64], partB[16][64];
    __shared__ int s_cnt0[16], s_cnt1[16];
    __shared__ int s_break;

    float (*accs)[14] = (float(*)[14])smem_u;
    unsigned* skey32 = (unsigned*)smem_u;
    float* params_lds = (float*)smem_u;           // 1024 rows x 8 floats (32B)

    const int tid = threadIdx.x;
    const int wid = tid >> 6, lane = tid & 63;
    const int bid = blockIdx.x;
    char* wsb = (char*)ws;
    unsigned* keyg = (unsigned*)(wsb + KEY_B);
    unsigned* flag1 = (unsigned*)(wsb + F1_B);
    unsigned* flag2 = (unsigned*)(wsb + F2_B);
    u64 lmask = (1ull << lane) - 1ull;

    // ================= phase A: this block's 8 gaussians =================
    {
        int gi = tid >> 7;             // 0..7
        int head = (tid >> 3) & 15;    // 0..15 (14,15 idle)
        int sub = tid & 7;             // 0..7
        int g = bid * 8 + gi;
        if (head < 14) {
            const float* wbase;
            if (head < 3)       wbase = w_shs + head * FEATN;
            else if (head < 6)  wbase = w_scale + (head - 3) * FEATN;
            else if (head < 9)  wbase = w_xyz + (head - 6) * FEATN;
            else if (head == 9) wbase = w_opac;
            else                wbase = w_rot + (head - 10) * FEATN;
            const float4* xp = (const float4*)(x + (size_t)g * FEATN + sub * 16);
            const float* wp = wbase + sub * 16;
            float acc = 0.0f;
#pragma unroll
            for (int k4 = 0; k4 < 4; k4++) {
                float4 xv = xp[k4];
                acc += xv.x * wp[k4 * 4 + 0] + xv.y * wp[k4 * 4 + 1]
                     + xv.z * wp[k4 * 4 + 2] + xv.w * wp[k4 * 4 + 3];
            }
            acc += __shfl_xor(acc, 1);
            acc += __shfl_xor(acc, 2);
            acc += __shfl_xor(acc, 4);
            if (sub == 0) accs[gi][head] = acc;
        }
    }
    __syncthreads();
    if (tid < 8) {     // all in wave 0
        int g = bid * 8 + tid;
        float acc[14];
#pragma unroll
        for (int j = 0; j < 14; j++) acc[j] = accs[tid][j];

        float r0 = sigmoidf_(acc[0] + b_shs[0]);
        float r1 = sigmoidf_(acc[1] + b_shs[1]);
        float r2 = sigmoidf_(acc[2] + b_shs[2]);
        float s0 = fminf(expf(acc[3] + b_scale[0]), 0.2f);
        float s1 = fminf(expf(acc[4] + b_scale[1]), 0.2f);
        float s2 = fminf(expf(acc[5] + b_scale[2]), 0.2f);
        float o0 = (sigmoidf_(acc[6] + b_xyz[0]) - 0.5f) * 0.05f;
        float o1 = (sigmoidf_(acc[7] + b_xyz[1]) - 0.5f) * 0.05f;
        float o2 = (sigmoidf_(acc[8] + b_xyz[2]) - 0.5f) * 0.05f;
        float opac = sigmoidf_(acc[9] + b_opac[0]);
        float qw = acc[10] + b_rot[0];
        float qx = acc[11] + b_rot[1];
        float qy = acc[12] + b_rot[2];
        float qz = acc[13] + b_rot[3];
        float qn = sqrtf(qw * qw + qx * qx + qy * qy + qz * qz);
        qw /= qn; qx /= qn; qy /= qn; qz /= qn;

        float R[3][3];
        R[0][0] = 1.f - 2.f * (qy * qy + qz * qz);
        R[0][1] = 2.f * (qx * qy - qw * qz);
        R[0][2] = 2.f * (qx * qz + qw * qy);
        R[1][0] = 2.f * (qx * qy + qw * qz);
        R[1][1] = 1.f - 2.f * (qx * qx + qz * qz);
        R[1][2] = 2.f * (qy * qz - qw * qx);
        R[2][0] = 2.f * (qx * qz - qw * qy);
        R[2][1] = 2.f * (qy * qz + qw * qx);
        R[2][2] = 1.f - 2.f * (qx * qx + qy * qy);

        float sq[3] = { s0 * s0, s1 * s1, s2 * s2 };
        float cov[3][3];
#pragma unroll
        for (int i = 0; i < 3; i++)
#pragma unroll
            for (int k = 0; k < 3; k++)
                cov[i][k] = R[i][0] * sq[0] * R[k][0] + R[i][1] * sq[1] * R[k][1] + R[i][2] * sq[2] * R[k][2];

        float Rv[3][3], tv[3];
#pragma unroll
        for (int i = 0; i < 3; i++) {
#pragma unroll
            for (int j = 0; j < 3; j++) Rv[i][j] = vm[i * 4 + j];
            tv[i] = vm[i * 4 + 3];
        }
        float X0 = pts[g * 3 + 0] + o0;
        float X1 = pts[g * 3 + 1] + o1;
        float X2 = pts[g * 3 + 2] + o2;
        float p0 = Rv[0][0] * X0 + Rv[0][1] * X1 + Rv[0][2] * X2 + tv[0];
        float p1 = Rv[1][0] * X0 + Rv[1][1] * X1 + Rv[1][2] * X2 + tv[1];
        float p2 = Rv[2][0] * X0 + Rv[2][1] * X1 + Rv[2][2] * X2 + tv[2];
        float tz = fmaxf(p2, 0.001f);
        float u = 128.0f * p0 / tz + 64.0f;
        float v = 128.0f * p1 / tz + 64.0f;

        float j00 = 128.0f / tz, j02 = -128.0f * p0 / (tz * tz);
        float j11 = 128.0f / tz, j12 = -128.0f * p1 / (tz * tz);
        float M0[3], M1[3];
#pragma unroll
        for (int k = 0; k < 3; k++) {
            M0[k] = j00 * Rv[0][k] + j02 * Rv[2][k];
            M1[k] = j11 * Rv[1][k] + j12 * Rv[2][k];
        }
        float t0[3], t1[3];
#pragma unroll
        for (int k = 0; k < 3; k++) {
            t0[k] = M0[0] * cov[0][k] + M0[1] * cov[1][k] + M0[2] * cov[2][k];
            t1[k] = M1[0] * cov[0][k] + M1[1] * cov[1][k] + M1[2] * cov[2][k];
        }
        float A = t0[0] * M0[0] + t0[1] * M0[1] + t0[2] * M0[2] + 0.3f;
        float B = t0[0] * M1[0] + t0[1] * M1[1] + t0[2] * M1[2];
        float C = t1[0] * M1[0] + t1[1] * M1[1] + t1[2] * M1[2] + 0.3f;
        float det = A * C - B * B + 1e-12f;
        float cA = C / det, cB = -B / det, cC = A / det;

        if (p2 <= 0.01f) opac = 0.0f;

        float rx, ry;
        if (opac >= 1.0f / 255.0f) {
            float L = 2.0f * logf(255.0f * opac);
            rx = sqrtf(L * A) + 0.6f;   // +0.6: 0.5 pixel-center pad + f16 rounding margin
            ry = sqrtf(L * C) + 0.6f;
        } else {
            rx = -1e9f; ry = -1e9f;     // -> f16 -inf: never kept
        }

        // cull record: f16x4
        u64 h0 = (u64)__half_as_ushort(__float2half(u))
               | ((u64)__half_as_ushort(__float2half(v)) << 16)
               | ((u64)__half_as_ushort(__float2half(rx)) << 32)
               | ((u64)__half_as_ushort(__float2half(ry)) << 48);
        stg8(wsb + (size_t)g * 8, h0);
        st_f4(wsb + RAW1_B + (size_t)g * 16,
              make_float4(u, v, -0.5f * LOG2E * cA, -LOG2E * cB));
        unsigned rg = (unsigned)bf16_(r0) | ((unsigned)bf16_(r1) << 16);
        st_f4(wsb + RAW2_B + (size_t)g * 16,
              make_float4(-0.5f * LOG2E * cC, opac, __uint_as_float(rg), r2));
        stg4(&keyg[g], __float_as_uint(tz));   // tz > 0 -> bits monotone
    }

    // ---- barrier 1: raw params + keys visible ----
    asm volatile("s_waitcnt vmcnt(0)" ::: "memory");
    __syncthreads();
    if (tid == 0) stg4(&flag1[bid], MAGIC1);
    if (tid < 256) {
        while (ldg4(&flag1[tid]) != MAGIC1) __builtin_amdgcn_s_sleep(4);
    }
    __syncthreads();

    // ================= rank + scatter: this block's 8 gaussians =================
    ((u64*)skey32)[tid] = ((const u64*)keyg)[tid];   // plain cached read
    __syncthreads();
    if (wid < 8) {
        int g = bid * 8 + wid;
        unsigned mk = skey32[g];
        const uint4* p4 = (const uint4*)skey32;
        int cnt = 0;
#pragma unroll
        for (int q = 0; q < 8; ++q) {              // conflict-free b128, 4 keys each
            int jb = lane + (q << 6);
            uint4 kv = p4[jb];
            int j0 = jb << 2;
            cnt += (kv.x < mk || (kv.x == mk && (j0 + 0) < g)) ? 1 : 0;
            cnt += (kv.y < mk || (kv.y == mk && (j0 + 1) < g)) ? 1 : 0;
            cnt += (kv.z < mk || (kv.z == mk && (j0 + 2) < g)) ? 1 : 0;
            cnt += (kv.w < mk || (kv.w == mk && (j0 + 3) < g)) ? 1 : 0;
        }
        cnt += __shfl_xor(cnt, 1);
        cnt += __shfl_xor(cnt, 2);
        cnt += __shfl_xor(cnt, 4);
        cnt += __shfl_xor(cnt, 8);
        cnt += __shfl_xor(cnt, 16);
        cnt += __shfl_xor(cnt, 32);                // every lane has the rank
        if (lane < 5) {                            // copy 40B record to sorted slots
            u64 v; char* dst;
            if (lane == 0) {
                v = *(const u64*)(wsb + (size_t)g * 8);
                dst = wsb + S0_B + (size_t)cnt * 8;
            } else {
                int ai = (lane - 1) >> 1, hf = (lane - 1) & 1;
                v = *(const u64*)(wsb + (ai ? RAW2_B : RAW1_B) + (size_t)g * 16 + hf * 8);
                dst = wsb + (ai ? S2_B : S1_B) + (size_t)cnt * 16 + hf * 8;
            }
            stg8(dst, v);
        }
    }

    // ---- barrier 2: sorted arrays visible ----
    asm volatile("s_waitcnt vmcnt(0)" ::: "memory");
    __syncthreads();
    if (tid == 0) stg4(&flag2[bid], MAGIC2);
    if (tid < 256) {
        while (ldg4(&flag2[tid]) != MAGIC2) __builtin_amdgcn_s_sleep(4);
    }
    __syncthreads();

    // ================= phase B: render tile bid (plain cached reads) =============
    const u64* S0_64 = (const u64*)(wsb + S0_B);
    const float4* S1_4 = (const float4*)(wsb + S1_B);
    const float4* S2_4 = (const float4*)(wsb + S2_B);
    int tx0 = (bid & 15) << 3, ty0 = (bid >> 4) << 3;
    float x0 = tx0 + 0.5f, x1 = tx0 + 7.5f;
    float y0 = ty0 + 0.5f, y1 = ty0 + 7.5f;

    // single-pass cull over depth-sorted cull records (compaction keeps depth order)
    int n;
    {
        int sA = tid, sB = tid + 1024;
        u64 pa = S0_64[sA], pb = S0_64[sB];
        float ua = __half2float(__ushort_as_half((unsigned short)pa));
        float va = __half2float(__ushort_as_half((unsigned short)(pa >> 16)));
        float ra = __half2float(__ushort_as_half((unsigned short)(pa >> 32)));
        float ya = __half2float(__ushort_as_half((unsigned short)(pa >> 48)));
        float ub = __half2float(__ushort_as_half((unsigned short)pb));
        float vb = __half2float(__ushort_as_half((unsigned short)(pb >> 16)));
        float rb = __half2float(__ushort_as_half((unsigned short)(pb >> 32)));
        float yb = __half2float(__ushort_as_half((unsigned short)(pb >> 48)));
        bool kA = (ua + ra >= x0) && (ua - ra <= x1) && (va + ya >= y0) && (va - ya <= y1);
        bool kB = (ub + rb >= x0) && (ub - rb <= x1) && (vb + yb >= y0) && (vb - yb <= y1);
        u64 m0 = __ballot(kA), m1 = __ballot(kB);
        if (lane == 0) { s_cnt0[wid] = __popcll(m0); s_cnt1[wid] = __popcll(m1); }
        __syncthreads();
        int b0 = 0, t0 = 0, b1 = 0, t1 = 0;
#pragma unroll
        for (int w = 0; w < 16; w++) {
            if (w < wid) { b0 += s_cnt0[w]; b1 += s_cnt1[w]; }
            t0 += s_cnt0[w]; t1 += s_cnt1[w];
        }
        if (kA) sidx16[b0 + __popcll(m0 & lmask)] = (unsigned short)sA;
        if (kB) sidx16[t0 + b1 + __popcll(m1 & lmask)] = (unsigned short)sB;
        n = t0 + t1;
        __syncthreads();
    }

    // chunks of 1024 ranks: fetch (32B/splat) -> 16-way segmented composite -> combine
    float gx = x0 + (float)(lane & 7);
    float gy = y0 + (float)(lane >> 3);
    float crT = 1.0f, crR = 0.0f, crG = 0.0f, crB = 0.0f;   // carry in wave-0 regs
    for (int c0 = 0; c0 < n; c0 += 1024) {
        int m = min(1024, n - c0);
        if (tid < m) {
            int s = sidx16[c0 + tid];
            float4 a = S1_4[s];
            float4 b = S2_4[s];
            float4* e = (float4*)(params_lds + tid * 8);
            e[0] = a;    // u,v,a2,b2
            e[1] = b;    // c2,op,rg,b
        }
        __syncthreads();

        int seg = (m + 15) >> 4;
        int sb = wid * seg;
        int se = min(m, sb + seg);
        float T = 1.0f, oR = 0.0f, oG = 0.0f, oB = 0.0f;
        for (int i = sb; i < se; ++i) {
            const float4* e = (const float4*)(params_lds + i * 8);
            float4 e0 = e[0];
            float4 e1 = e[1];
            float dx = gx - e0.x, dy = gy - e0.y;
            float pw = dx * (e0.z * dx + e0.w * dy) + e1.x * dy * dy;  // log2-domain
            pw = fminf(pw, 0.0f);
            float al = fminf(0.99f, e1.y * exp2f(pw));
            al = (al < 1.0f / 255.0f) ? 0.0f : al;
            float w = al * T;
            unsigned rgb = __float_as_uint(e1.z);
            oR += w * __uint_as_float(rgb << 16);
            oG += w * __uint_as_float(rgb & 0xffff0000u);
            oB += w * e1.w;
            T -= al * T;
        }
        partT[wid][lane] = T;
        partR[wid][lane] = oR;
        partG[wid][lane] = oG;
        partB[wid][lane] = oB;
        __syncthreads();

        if (wid == 0) {
#pragma unroll
            for (int w = 0; w < 16; w++) {
                crR += crT * partR[w][lane];
                crG += crT * partG[w][lane];
                crB += crT * partB[w][lane];
                crT *= partT[w][lane];
            }
            u64 alive = __ballot(crT >= 1.5e-5f);
            if (lane == 0) s_break = (alive == 0ull);
        }
        __syncthreads();
        if (s_break) break;    // all 64 pixels saturated; residual <= 1.5e-5
    }

    if (wid == 0) {
        int p = (ty0 + (lane >> 3)) * 128 + tx0 + (lane & 7);
        out[p * 3 + 0] = crR;
        out[p * 3 + 1] = crG;
        out[p * 3 + 2] = crB;
    }
}

extern "C" void kernel_launch(void* const* d_in, const int* in_sizes, int n_in,
                              void* d_out, int out_size, void* d_ws, size_t ws_size,
                              hipStream_t stream)
{
    const float* x       = (const float*)d_in[0];
    const float* pts     = (const float*)d_in[1];
    const float* viewmat = (const float*)d_in[2];
    const float* w_shs   = (const float*)d_in[3];
    const float* b_shs   = (const float*)d_in[4];
    const float* w_scale = (const float*)d_in[5];
    const float* b_scale = (const float*)d_in[6];
    const float* w_xyz   = (const float*)d_in[7];
    const float* b_xyz   = (const float*)d_in[8];
    const float* w_opac  = (const float*)d_in[9];
    const float* b_opac  = (const float*)d_in[10];
    const float* w_rot   = (const float*)d_in[11];
    const float* b_rot   = (const float*)d_in[12];
    float* ws = (float*)d_ws;
    float* out = (float*)d_out;

    k_fused<<<NBLK, 1024, 0, stream>>>(x, pts, viewmat, w_shs, b_shs, w_scale, b_scale,
                                       w_xyz, b_xyz, w_opac, b_opac, w_rot, b_rot, ws, out);
}

// Round 17
// 24.823 us; speedup vs baseline: 1.0379x; 1.0379x over previous
//
#include <hip/hip_runtime.h>
#include <math.h>

#define NG 2048
#define FEATN 128
#define NBLK 256
#define LOG2E 1.4426950408889634f
#define MAGIC1 0x7F3DC0DEu
#define MAGIC2 0x6B42F00Du

typedef unsigned long long u64;

// ws byte layout:
//   RA f4[2048] @0       {u,v,rx,ry}
//   RB f4[2048] @32768   {a2,b2,c2,op}
//   RC f4[2048] @65536   {r,g,b,0}
//   KEY u32[2048] @98304 (tz bits; ties broken by index)
//   SORT (SA/SB/SC, stride 32768) @131072
//   FLAG1 u32[256] @229376 | FLAG2 u32[256] @230400
#define RB_BYTE   32768
#define RC_BYTE   65536
#define KEY_BYTE  98304
#define SORT_BYTE 131072
#define F1_BYTE   229376
#define F2_BYTE   230400

__device__ __forceinline__ float sigmoidf_(float z) { return 1.0f / (1.0f + expf(-z)); }

// Cross-XCD write path: relaxed agent-scope atomic stores (L1/L2-bypass -> LLC).
// Read path after barriers uses PLAIN cached loads: L2 invalidated at dispatch
// start + no pre-barrier cached reads of these lines => first read pulls the
// final value from LLC; replay-stale content is bit-identical (deterministic).
__device__ __forceinline__ void stg8(void* p, u64 v) {
    __hip_atomic_store((u64*)p, v, __ATOMIC_RELAXED, __HIP_MEMORY_SCOPE_AGENT);
}
__device__ __forceinline__ void stg4(unsigned* p, unsigned v) {
    __hip_atomic_store(p, v, __ATOMIC_RELAXED, __HIP_MEMORY_SCOPE_AGENT);
}
__device__ __forceinline__ unsigned ldg4(const unsigned* p) {
    return __hip_atomic_load(p, __ATOMIC_RELAXED, __HIP_MEMORY_SCOPE_AGENT);
}
__device__ __forceinline__ void st_f4(void* p, float4 v) {
    union { float2 f; u64 u; } a, b;
    a.f = make_float2(v.x, v.y); b.f = make_float2(v.z, v.w);
    stg8(p, a.u); stg8((char*)p + 8, b.u);
}

__global__ __launch_bounds__(1024) void k_fused(
    const float* __restrict__ x, const float* __restrict__ pts, const float* __restrict__ vm,
    const float* __restrict__ w_shs, const float* __restrict__ b_shs,
    const float* __restrict__ w_scale, const float* __restrict__ b_scale,
    const float* __restrict__ w_xyz, const float* __restrict__ b_xyz,
    const float* __restrict__ w_opac, const float* __restrict__ b_opac,
    const float* __restrict__ w_rot, const float* __restrict__ b_rot,
    float* __restrict__ ws, float* __restrict__ out)
{
    // smem_u overlays: phaseA {sw[1792]f, accs[8][14]f} | rank {skey32 u32[2048]} | phaseB params_lds[1024][12]f
    __shared__ __attribute__((aligned(16))) char smem_u[1024 * 12 * 4];
    __shared__ unsigned short sidx16[NG];
    __shared__ float partT[16][64], partR[16][64], partG[16][64], partB[16][64];
    __shared__ int s_cnt[16];
    __shared__ int s_break;

    float* sw = (float*)smem_u;
    float (*accs)[14] = (float(*)[14])(smem_u + 7168);
    unsigned* skey32 = (unsigned*)smem_u;
    float (*params_lds)[12] = (float(*)[12])smem_u;

    const int tid = threadIdx.x;
    const int wid = tid >> 6, lane = tid & 63;
    const int bid = blockIdx.x;
    char* wsb = (char*)ws;
    unsigned* keyg = (unsigned*)(wsb + KEY_BYTE);
    unsigned* flag1 = (unsigned*)(wsb + F1_BYTE);
    unsigned* flag2 = (unsigned*)(wsb + F2_BYTE);
    u64 lmask = (1ull << lane) - 1ull;

    // ================= phase A: this block's 8 gaussians =================
    for (int i = tid; i < 14 * FEATN; i += 1024) {
        int r = i >> 7, c0 = i & 127;
        float v;
        if (r < 3)       v = w_shs[r * FEATN + c0];
        else if (r < 6)  v = w_scale[(r - 3) * FEATN + c0];
        else if (r < 9)  v = w_xyz[(r - 6) * FEATN + c0];
        else if (r == 9) v = w_opac[c0];
        else             v = w_rot[(r - 10) * FEATN + c0];
        sw[i] = v;
    }
    __syncthreads();
    {
        int gi = tid >> 7;             // 0..7
        int head = (tid >> 3) & 15;    // 0..15 (14,15 idle)
        int sub = tid & 7;             // 0..7
        int g = bid * 8 + gi;
        if (head < 14) {
            const float4* xp = (const float4*)(x + (size_t)g * FEATN + sub * 16);
            const float* wp = sw + head * FEATN + sub * 16;
            float acc = 0.0f;
#pragma unroll
            for (int k4 = 0; k4 < 4; k4++) {
                float4 xv = xp[k4];
                acc += xv.x * wp[k4 * 4 + 0] + xv.y * wp[k4 * 4 + 1]
                     + xv.z * wp[k4 * 4 + 2] + xv.w * wp[k4 * 4 + 3];
            }
            acc += __shfl_xor(acc, 1);
            acc += __shfl_xor(acc, 2);
            acc += __shfl_xor(acc, 4);
            if (sub == 0) accs[gi][head] = acc;
        }
    }
    __syncthreads();
    if (tid < 8) {     // all in wave 0
        int g = bid * 8 + tid;
        float acc[14];
#pragma unroll
        for (int j = 0; j < 14; j++) acc[j] = accs[tid][j];

        float r0 = sigmoidf_(acc[0] + b_shs[0]);
        float r1 = sigmoidf_(acc[1] + b_shs[1]);
        float r2 = sigmoidf_(acc[2] + b_shs[2]);
        float s0 = fminf(expf(acc[3] + b_scale[0]), 0.2f);
        float s1 = fminf(expf(acc[4] + b_scale[1]), 0.2f);
        float s2 = fminf(expf(acc[5] + b_scale[2]), 0.2f);
        float o0 = (sigmoidf_(acc[6] + b_xyz[0]) - 0.5f) * 0.05f;
        float o1 = (sigmoidf_(acc[7] + b_xyz[1]) - 0.5f) * 0.05f;
        float o2 = (sigmoidf_(acc[8] + b_xyz[2]) - 0.5f) * 0.05f;
        float opac = sigmoidf_(acc[9] + b_opac[0]);
        float qw = acc[10] + b_rot[0];
        float qx = acc[11] + b_rot[1];
        float qy = acc[12] + b_rot[2];
        float qz = acc[13] + b_rot[3];
        float qn = sqrtf(qw * qw + qx * qx + qy * qy + qz * qz);
        qw /= qn; qx /= qn; qy /= qn; qz /= qn;

        float R[3][3];
        R[0][0] = 1.f - 2.f * (qy * qy + qz * qz);
        R[0][1] = 2.f * (qx * qy - qw * qz);
        R[0][2] = 2.f * (qx * qz + qw * qy);
        R[1][0] = 2.f * (qx * qy + qw * qz);
        R[1][1] = 1.f - 2.f * (qx * qx + qz * qz);
        R[1][2] = 2.f * (qy * qz - qw * qx);
        R[2][0] = 2.f * (qx * qz - qw * qy);
        R[2][1] = 2.f * (qy * qz + qw * qx);
        R[2][2] = 1.f - 2.f * (qx * qx + qy * qy);

        float sq[3] = { s0 * s0, s1 * s1, s2 * s2 };
        float cov[3][3];
#pragma unroll
        for (int i = 0; i < 3; i++)
#pragma unroll
            for (int k = 0; k < 3; k++)
                cov[i][k] = R[i][0] * sq[0] * R[k][0] + R[i][1] * sq[1] * R[k][1] + R[i][2] * sq[2] * R[k][2];

        float Rv[3][3], tv[3];
#pragma unroll
        for (int i = 0; i < 3; i++) {
#pragma unroll
            for (int j = 0; j < 3; j++) Rv[i][j] = vm[i * 4 + j];
            tv[i] = vm[i * 4 + 3];
        }
        float X0 = pts[g * 3 + 0] + o0;
        float X1 = pts[g * 3 + 1] + o1;
        float X2 = pts[g * 3 + 2] + o2;
        float p0 = Rv[0][0] * X0 + Rv[0][1] * X1 + Rv[0][2] * X2 + tv[0];
        float p1 = Rv[1][0] * X0 + Rv[1][1] * X1 + Rv[1][2] * X2 + tv[1];
        float p2 = Rv[2][0] * X0 + Rv[2][1] * X1 + Rv[2][2] * X2 + tv[2];
        float tz = fmaxf(p2, 0.001f);
        float u = 128.0f * p0 / tz + 64.0f;
        float v = 128.0f * p1 / tz + 64.0f;

        float j00 = 128.0f / tz, j02 = -128.0f * p0 / (tz * tz);
        float j11 = 128.0f / tz, j12 = -128.0f * p1 / (tz * tz);
        float M0[3], M1[3];
#pragma unroll
        for (int k = 0; k < 3; k++) {
            M0[k] = j00 * Rv[0][k] + j02 * Rv[2][k];
            M1[k] = j11 * Rv[1][k] + j12 * Rv[2][k];
        }
        float t0[3], t1[3];
#pragma unroll
        for (int k = 0; k < 3; k++) {
            t0[k] = M0[0] * cov[0][k] + M0[1] * cov[1][k] + M0[2] * cov[2][k];
            t1[k] = M1[0] * cov[0][k] + M1[1] * cov[1][k] + M1[2] * cov[2][k];
        }
        float A = t0[0] * M0[0] + t0[1] * M0[1] + t0[2] * M0[2] + 0.3f;
        float B = t0[0] * M1[0] + t0[1] * M1[1] + t0[2] * M1[2];
        float C = t1[0] * M1[0] + t1[1] * M1[1] + t1[2] * M1[2] + 0.3f;
        float det = A * C - B * B + 1e-12f;
        float cA = C / det, cB = -B / det, cC = A / det;

        if (p2 <= 0.01f) opac = 0.0f;

        float rx, ry;
        if (opac >= 1.0f / 255.0f) {
            float L = 2.0f * logf(255.0f * opac);
            rx = sqrtf(L * A) + 0.5f;
            ry = sqrtf(L * C) + 0.5f;
        } else {
            rx = -1e9f; ry = -1e9f;
        }

        st_f4(wsb + (size_t)g * 16,            make_float4(u, v, rx, ry));
        st_f4(wsb + RB_BYTE + (size_t)g * 16,  make_float4(-0.5f * LOG2E * cA, -LOG2E * cB, -0.5f * LOG2E * cC, opac));
        st_f4(wsb + RC_BYTE + (size_t)g * 16,  make_float4(r0, r1, r2, 0.0f));
        stg4(&keyg[g], __float_as_uint(tz));   // tz > 0 -> bits monotone
    }

    // ---- barrier 1: raw params + keys visible ----
    asm volatile("s_waitcnt vmcnt(0)" ::: "memory");
    __syncthreads();
    if (tid == 0) stg4(&flag1[bid], MAGIC1);
    if (tid < 256) {
        while (ldg4(&flag1[tid]) != MAGIC1) __builtin_amdgcn_s_sleep(4);
    }
    __syncthreads();

    // ================= rank + scatter (plain cached reads post-barrier) =========
    ((u64*)skey32)[tid] = ((const u64*)keyg)[tid];
    __syncthreads();
    if (wid < 8) {
        int g = bid * 8 + wid;
        unsigned mk = skey32[g];
        const uint4* p4 = (const uint4*)skey32;
        int cnt = 0;
#pragma unroll
        for (int q = 0; q < 8; ++q) {              // conflict-free b128, 4 keys each
            int jb = lane + (q << 6);
            uint4 kv = p4[jb];
            int j0 = jb << 2;
            cnt += (kv.x < mk || (kv.x == mk && (j0 + 0) < g)) ? 1 : 0;
            cnt += (kv.y < mk || (kv.y == mk && (j0 + 1) < g)) ? 1 : 0;
            cnt += (kv.z < mk || (kv.z == mk && (j0 + 2) < g)) ? 1 : 0;
            cnt += (kv.w < mk || (kv.w == mk && (j0 + 3) < g)) ? 1 : 0;
        }
        cnt += __shfl_xor(cnt, 1);
        cnt += __shfl_xor(cnt, 2);
        cnt += __shfl_xor(cnt, 4);
        cnt += __shfl_xor(cnt, 8);
        cnt += __shfl_xor(cnt, 16);
        cnt += __shfl_xor(cnt, 32);                // every lane has the rank
        if (lane < 6) {                            // copy 48B record to SORT[rank]
            const u64* src = (const u64*)(wsb + (lane >> 1) * 32768 + (size_t)g * 16 + (lane & 1) * 8);
            char* dst = wsb + SORT_BYTE + (lane >> 1) * 32768 + (size_t)cnt * 16 + (lane & 1) * 8;
            stg8(dst, *src);                       // cached read, bypassing store
        }
    }

    // ---- barrier 2: sorted arrays visible ----
    asm volatile("s_waitcnt vmcnt(0)" ::: "memory");
    __syncthreads();
    if (tid == 0) stg4(&flag2[bid], MAGIC2);
    if (tid < 256) {
        while (ldg4(&flag2[tid]) != MAGIC2) __builtin_amdgcn_s_sleep(4);
    }
    __syncthreads();

    // ================= phase B: render tile bid (plain cached reads) =============
    const float4* SA4 = (const float4*)(wsb + SORT_BYTE);
    const float4* SB4 = (const float4*)(wsb + SORT_BYTE + 32768);
    const float4* SC4 = (const float4*)(wsb + SORT_BYTE + 65536);
    int tx0 = (bid & 15) << 3, ty0 = (bid >> 4) << 3;
    float x0 = tx0 + 0.5f, x1 = tx0 + 7.5f;
    float y0 = ty0 + 0.5f, y1 = ty0 + 7.5f;

    // cull: compaction over depth-sorted arrays preserves depth order
    int n = 0;
#pragma unroll
    for (int r = 0; r < 2; ++r) {
        int s = r * 1024 + tid;
        float4 a = SA4[s];
        bool keep = (a.x + a.z >= x0) && (a.x - a.z <= x1) &&
                    (a.y + a.w >= y0) && (a.y - a.w <= y1);
        u64 m = __ballot(keep);
        if (lane == 0) s_cnt[wid] = __popcll(m);
        __syncthreads();
        int base = n, total = 0;
#pragma unroll
        for (int w = 0; w < 16; w++) {
            if (w < wid) base += s_cnt[w];
            total += s_cnt[w];
        }
        if (keep) sidx16[base + __popcll(m & lmask)] = (unsigned short)s;
        n += total;
        __syncthreads();
    }

    // chunks of 1024 ranks: fetch -> 16-way segmented composite -> carry combine -> break
    float gx = x0 + (float)(lane & 7);
    float gy = y0 + (float)(lane >> 3);
    float crT = 1.0f, crR = 0.0f, crG = 0.0f, crB = 0.0f;   // carry in wave-0 regs
    for (int c0 = 0; c0 < n; c0 += 1024) {
        int m = min(1024, n - c0);
        if (tid < m) {
            int s = sidx16[c0 + tid];
            float4 a = SA4[s];
            float4 b = SB4[s];
            float4 c = SC4[s];
            float* e = params_lds[tid];
            ((float4*)e)[0] = make_float4(a.x, a.y, b.x, b.y);   // u,v,a2,b2
            ((float4*)e)[1] = make_float4(b.z, b.w, c.x, c.y);   // c2,op,r,g
            e[8] = c.z;                                          // b
        }
        __syncthreads();

        int seg = (m + 15) >> 4;
        int sb = wid * seg;
        int se = min(m, sb + seg);
        float T = 1.0f, oR = 0.0f, oG = 0.0f, oB = 0.0f;
        for (int i = sb; i < se; ++i) {
            const float* e = params_lds[i];
            float4 e0 = ((const float4*)e)[0];
            float4 e1 = ((const float4*)e)[1];
            float bl = e[8];
            float dx = gx - e0.x, dy = gy - e0.y;
            float pw = dx * (e0.z * dx + e0.w * dy) + e1.x * dy * dy;  // log2-domain
            pw = fminf(pw, 0.0f);
            float al = fminf(0.99f, e1.y * exp2f(pw));
            al = (al < 1.0f / 255.0f) ? 0.0f : al;
            float w = al * T;
            oR += w * e1.z;
            oG += w * e1.w;
            oB += w * bl;
            T -= al * T;
        }
        partT[wid][lane] = T;
        partR[wid][lane] = oR;
        partG[wid][lane] = oG;
        partB[wid][lane] = oB;
        __syncthreads();

        if (wid == 0) {
#pragma unroll
            for (int w = 0; w < 16; w++) {
                crR += crT * partR[w][lane];
                crG += crT * partG[w][lane];
                crB += crT * partB[w][lane];
                crT *= partT[w][lane];
            }
            u64 alive = __ballot(crT >= 1.5e-5f);
            if (lane == 0) s_break = (alive == 0ull);
        }
        __syncthreads();
        if (s_break) break;    // all 64 pixels saturated; residual <= 1.5e-5
    }

    if (wid == 0) {
        int p = (ty0 + (lane >> 3)) * 128 + tx0 + (lane & 7);
        out[p * 3 + 0] = crR;
        out[p * 3 + 1] = crG;
        out[p * 3 + 2] = crB;
    }
}

extern "C" void kernel_launch(void* const* d_in, const int* in_sizes, int n_in,
                              void* d_out, int out_size, void* d_ws, size_t ws_size,
                              hipStream_t stream)
{
    const float* x       = (const float*)d_in[0];
    const float* pts     = (const float*)d_in[1];
    const float* viewmat = (const float*)d_in[2];
    const float* w_shs   = (const float*)d_in[3];
    const float* b_shs   = (const float*)d_in[4];
    const float* w_scale = (const float*)d_in[5];
    const float* b_scale = (const float*)d_in[6];
    const float* w_xyz   = (const float*)d_in[7];
    const float* b_xyz   = (const float*)d_in[8];
    const float* w_opac  = (const float*)d_in[9];
    const float* b_opac  = (const float*)d_in[10];
    const float* w_rot   = (const float*)d_in[11];
    const float* b_rot   = (const float*)d_in[12];
    float* ws = (float*)d_ws;
    float* out = (float*)d_out;

    k_fused<<<NBLK, 1024, 0, stream>>>(x, pts, viewmat, w_shs, b_shs, w_scale, b_scale,
                                       w_xyz, b_xyz, w_opac, b_opac, w_rot, b_rot, ws, out);
}